// Round 11
// baseline (309.827 us; speedup 1.0000x reference)
//
#include <hip/hip_runtime.h>

#define NB   4
#define NH   32
#define ND   128
#define NHID 4096
#define NSQ  4096
#define NSF  63
#define NST  4160      // NSQ + NSF + 1
#define NBH  128       // NB * NH

typedef int   v4i __attribute__((ext_vector_type(4)));
typedef float v4f __attribute__((ext_vector_type(4)));
typedef float v2f __attribute__((ext_vector_type(2)));

// ---------------------------------------------------------------------------
// GEMV: Y[b, j] = sum_i X[b, i] * W[j, i]   (W row-major HIDxHID)
// 8 rows per block, 4 batches simultaneously; X tile staged in LDS.
// ---------------------------------------------------------------------------
__device__ __forceinline__ void gemv8_body(const float* __restrict__ W,
                                           const float* __restrict__ X,
                                           float* __restrict__ Y,
                                           int blk) {
    __shared__ float4 xs[4][256];
    __shared__ float  wred[32][4];
    const int tid  = threadIdx.x;
    const int row0 = blk * 8;

    float acc[8][4];
#pragma unroll
    for (int r = 0; r < 8; ++r)
#pragma unroll
        for (int b = 0; b < 4; ++b) acc[r][b] = 0.f;

    for (int kt = 0; kt < 4; ++kt) {
        const int kb = kt * 1024;
#pragma unroll
        for (int b = 0; b < 4; ++b)
            xs[b][tid] = *(const float4*)(&X[b * NHID + kb + tid * 4]);
        __syncthreads();
#pragma unroll
        for (int r = 0; r < 8; ++r) {
            v4f w = __builtin_nontemporal_load(
                        (const v4f*)&W[(size_t)(row0 + r) * NHID + kb + tid * 4]);
#pragma unroll
            for (int b = 0; b < 4; ++b) {
                float4 x = xs[b][tid];
                acc[r][b] += w.x * x.x + w.y * x.y + w.z * x.z + w.w * x.w;
            }
        }
        __syncthreads();
    }

    const int lane = tid & 63, wave = tid >> 6;
#pragma unroll
    for (int o = 0; o < 32; ++o) {
        float v = acc[o >> 2][o & 3];
#pragma unroll
        for (int off = 32; off; off >>= 1) v += __shfl_down(v, off, 64);
        if (lane == 0) wred[o][wave] = v;
    }
    __syncthreads();
    if (tid < 32) {
        float v = wred[tid][0] + wred[tid][1] + wred[tid][2] + wred[tid][3];
        Y[(size_t)(tid & 3) * NHID + row0 + (tid >> 2)] = v;
    }
}

__global__ __launch_bounds__(256) void gemv8_kernel(const float* __restrict__ W,
                                                    const float* __restrict__ X,
                                                    float* __restrict__ Y) {
    gemv8_body(W, X, Y, blockIdx.x);
}

// grid = 1536: blocks [0,512) -> wq, [512,1024) -> wk, [1024,1536) -> wv
__global__ __launch_bounds__(256) void gemv8_qkv_kernel(const float* __restrict__ wq,
                                                        const float* __restrict__ wk,
                                                        const float* __restrict__ wv,
                                                        const float* __restrict__ X,
                                                        float* __restrict__ q,
                                                        float* __restrict__ k,
                                                        float* __restrict__ v) {
    const int which = blockIdx.x >> 9;
    const int blk   = blockIdx.x & 511;
    const float* W = (which == 0) ? wq : (which == 1) ? wk : wv;
    float*       Y = (which == 0) ? q  : (which == 1) ? k  : v;
    gemv8_body(W, X, Y, blk);
}

// ---------------------------------------------------------------------------
// Fused flash split + inline RoPE + last-block finish.
// grid = NBH*4, 256 threads.
// ---------------------------------------------------------------------------
__global__ __launch_bounds__(256) void fused_attn_kernel(const int*   __restrict__ kq,
                                                         const float* __restrict__ ksc,
                                                         const float* __restrict__ kmn,
                                                         const float* __restrict__ keyp,
                                                         const int*   __restrict__ vq,
                                                         const float* __restrict__ vsc,
                                                         const float* __restrict__ vmn,
                                                         const float* __restrict__ valq,
                                                         const float* __restrict__ q_raw,
                                                         const float* __restrict__ k_raw,
                                                         const float* __restrict__ v_raw,
                                                         const int*   __restrict__ pos_ids,
                                                         const float* __restrict__ keyq,
                                                         const float* __restrict__ kfull,
                                                         const float* __restrict__ valp,
                                                         const float* __restrict__ vfull,
                                                         float* __restrict__ tailsc,
                                                         float* __restrict__ stats,
                                                         float* __restrict__ pout,
                                                         float* __restrict__ ppr,
                                                         int*   __restrict__ counters,
                                                         float* __restrict__ attn_out) {
    const int bh     = blockIdx.x >> 2;
    const int chunk  = blockIdx.x & 3;
    const int tid    = threadIdx.x;
    const int b      = bh >> 5;
    const int base   = bh * ND;
    const int gbase  = chunk * 16;
    const int schunk = chunk * 1024;

    __shared__ float  qsh[128], ksh[128];
    __shared__ float4 rred[128];
    __shared__ float  qr4v[4];
    __shared__ float  qs[128][16];     // q[d] * k_scale[d][g]
    __shared__ float  mt[128][16];     // q[d] * k_mn[d][g] -> reduced over d
    __shared__ float  psc[1024][2];    // p[s] * v_scale[s][g]
    __shared__ float  sred[256];
    __shared__ float2 red2[256];
    __shared__ float4 red4[256];
    __shared__ float  pmn2[2];
    __shared__ int    ticket;

    // ---- phase 0: inline RoPE + qr reduction ----
    if (tid < 128) {
        const int d = tid;
        const double pos  = (double)pos_ids[b];              // QL == 1
        const int    j    = d & 63;
        const double invf = pow(10000.0, -(double)(2 * j) / 128.0);
        const double ang  = pos * invf;
        const float  c = (float)cos(ang), s = (float)sin(ang);

        const float qv = q_raw[base + d], kv = k_raw[base + d];
        const float qh = (d < 64) ? -q_raw[base + d + 64] : q_raw[base + d - 64];
        const float kh = (d < 64) ? -k_raw[base + d + 64] : k_raw[base + d - 64];
        const float qo = qv * c + qh * s;
        const float ko = kv * c + kh * s;
        qsh[d] = qo;
        ksh[d] = ko;

        float4 kq4 = *(const float4*)(&keyq[(size_t)(base + d) * 4]);
        rred[d] = make_float4(qo * kq4.x, qo * kq4.y, qo * kq4.z, qo * kq4.w);
    }
    __syncthreads();
    for (int st = 64; st; st >>= 1) {
        if (tid < st) {
            rred[tid].x += rred[tid + st].x; rred[tid].y += rred[tid + st].y;
            rred[tid].z += rred[tid + st].z; rred[tid].w += rred[tid + st].w;
        }
        __syncthreads();
    }
    if (tid == 0) {
        qr4v[0] = rred[0].x; qr4v[1] = rred[0].y;
        qr4v[2] = rred[0].z; qr4v[3] = rred[0].w;
    }

    // ---- chunk 0 extra: raw tail scores (k_full rows + new roped k) ----
    if (chunk == 0) {
        const int lane = tid & 63, wave = tid >> 6;
        for (int t = wave; t < 64; t += 4) {
            const int d = lane * 2;
            float v;
            if (t < 63) {
                v2f r2 = __builtin_nontemporal_load(
                             (const v2f*)&kfull[((size_t)bh * NSF + t) * ND + d]);
                v = qsh[d] * r2.x + qsh[d + 1] * r2.y;
            } else {
                v = qsh[d] * ksh[d] + qsh[d + 1] * ksh[d + 1];
            }
#pragma unroll
            for (int off = 32; off; off >>= 1) v += __shfl_down(v, off, 64);
            if (lane == 0) tailsc[bh * 64 + t] = v * 0.08838834764831845f;
        }
    }
    __syncthreads();

    // ---- phase a: stage q*scale, reduce q*mn over d ----
    {
        const int d = tid >> 1, half = tid & 1;
        const float q = qsh[d];
        const float* scp = &ksc[((size_t)bh * ND + d) * 64 + gbase + half * 8];
        const float* mnp = &kmn[((size_t)bh * ND + d) * 64 + gbase + half * 8];
        v4f a = __builtin_nontemporal_load((const v4f*)(scp));
        v4f c = __builtin_nontemporal_load((const v4f*)(scp + 4));
        qs[d][half * 8 + 0] = q * a.x; qs[d][half * 8 + 1] = q * a.y;
        qs[d][half * 8 + 2] = q * a.z; qs[d][half * 8 + 3] = q * a.w;
        qs[d][half * 8 + 4] = q * c.x; qs[d][half * 8 + 5] = q * c.y;
        qs[d][half * 8 + 6] = q * c.z; qs[d][half * 8 + 7] = q * c.w;
        v4f m0 = __builtin_nontemporal_load((const v4f*)(mnp));
        v4f m1 = __builtin_nontemporal_load((const v4f*)(mnp + 4));
        mt[d][half * 8 + 0] = q * m0.x; mt[d][half * 8 + 1] = q * m0.y;
        mt[d][half * 8 + 2] = q * m0.z; mt[d][half * 8 + 3] = q * m0.w;
        mt[d][half * 8 + 4] = q * m1.x; mt[d][half * 8 + 5] = q * m1.y;
        mt[d][half * 8 + 6] = q * m1.z; mt[d][half * 8 + 7] = q * m1.w;
    }
    __syncthreads();
    for (int st = 64; st; st >>= 1) {
        for (int idx = tid; idx < st * 16; idx += 256) {
            const int dd = idx >> 4, g = idx & 15;
            mt[dd][g] += mt[dd + st][g];
        }
        __syncthreads();
    }

    // ---- phase b: scores for s0..s0+3 ----
    const int s0 = schunk + tid * 4;
    const int g  = tid >> 4;
    const int* kcol = kq + (size_t)bh * ND * NSQ + s0;

    float a0 = 0.f, a1 = 0.f, a2 = 0.f, a3 = 0.f;
#pragma unroll 8
    for (int d = 0; d < ND; ++d) {
        v4i c = __builtin_nontemporal_load((const v4i*)&kcol[(size_t)d * NSQ]);
        const float w = qs[d][g];
        a0 += w * (float)c.x; a1 += w * (float)c.y;
        a2 += w * (float)c.z; a3 += w * (float)c.w;
    }
    const float mnsum = mt[0][g];
    const float4 q4 = make_float4(qr4v[0], qr4v[1], qr4v[2], qr4v[3]);

    float sc4[4] = {a0, a1, a2, a3};
#pragma unroll
    for (int j = 0; j < 4; ++j) {
        v4f kp = __builtin_nontemporal_load(
                     (const v4f*)&keyp[((size_t)bh * NSQ + s0 + j) * 4]);
        sc4[j] = (sc4[j] + mnsum + q4.x * kp.x + q4.y * kp.y + q4.z * kp.z + q4.w * kp.w)
                 * 0.08838834764831845f;
    }

    // ---- phase c: local softmax over this block's 1024 scores ----
    float mloc = fmaxf(fmaxf(sc4[0], sc4[1]), fmaxf(sc4[2], sc4[3]));
    sred[tid] = mloc; __syncthreads();
    for (int st = 128; st; st >>= 1) {
        if (tid < st) sred[tid] = fmaxf(sred[tid], sred[tid + st]);
        __syncthreads();
    }
    mloc = sred[0]; __syncthreads();

    float p[4];
    float z = 0.f;
#pragma unroll
    for (int j = 0; j < 4; ++j) { p[j] = expf(sc4[j] - mloc); z += p[j]; }

    const int l0 = tid * 4;
    float2 pmn_loc = make_float2(0.f, 0.f);
    float4 pr4 = make_float4(0.f, 0.f, 0.f, 0.f);
#pragma unroll
    for (int j = 0; j < 4; ++j) {
        const int s = s0 + j;
        v2f sc = __builtin_nontemporal_load((const v2f*)&vsc[((size_t)bh * NSQ + s) * 2]);
        v2f mn = __builtin_nontemporal_load((const v2f*)&vmn[((size_t)bh * NSQ + s) * 2]);
        psc[l0 + j][0] = p[j] * sc.x;
        psc[l0 + j][1] = p[j] * sc.y;
        pmn_loc.x += p[j] * mn.x; pmn_loc.y += p[j] * mn.y;
        v4f vr = __builtin_nontemporal_load((const v4f*)&valq[((size_t)bh * NSQ + s) * 4]);
        pr4.x += p[j] * vr.x; pr4.y += p[j] * vr.y;
        pr4.z += p[j] * vr.z; pr4.w += p[j] * vr.w;
    }
    sred[tid] = z; red2[tid] = pmn_loc; red4[tid] = pr4;
    __syncthreads();
    for (int st = 128; st; st >>= 1) {
        if (tid < st) {
            sred[tid] += sred[tid + st];
            red2[tid].x += red2[tid + st].x; red2[tid].y += red2[tid + st].y;
            red4[tid].x += red4[tid + st].x; red4[tid].y += red4[tid + st].y;
            red4[tid].z += red4[tid + st].z; red4[tid].w += red4[tid + st].w;
        }
        __syncthreads();
    }
    if (tid == 0) {
        stats[(size_t)(bh * 4 + chunk) * 2]     = mloc;
        stats[(size_t)(bh * 4 + chunk) * 2 + 1] = sred[0];
        *(float4*)(&ppr[(size_t)(bh * 4 + chunk) * 4]) = red4[0];
        pmn2[0] = red2[0].x; pmn2[1] = red2[0].y;
    }
    __syncthreads();

    // ---- phase d: quantized-V partial over 1024 s-rows ----
    const int r      = tid >> 5;
    const int lane32 = tid & 31;
    const int d4     = lane32 * 4;
    const int gv     = lane32 >> 4;

    const int* vbase = vq + ((size_t)bh * NSQ + schunk) * ND + d4;

    float4 acc = make_float4(0.f, 0.f, 0.f, 0.f);
#pragma unroll 8
    for (int k0 = 0; k0 < 1024; k0 += 8) {
        const int kk = k0 + r;
        v4i c = __builtin_nontemporal_load((const v4i*)&vbase[(size_t)kk * ND]);
        const float w = psc[kk][gv];
        acc.x += w * (float)c.x; acc.y += w * (float)c.y;
        acc.z += w * (float)c.z; acc.w += w * (float)c.w;
    }
    red4[tid] = acc;
    __syncthreads();
    for (int st = 128; st >= 32; st >>= 1) {
        if (tid < st) {
            red4[tid].x += red4[tid + st].x; red4[tid].y += red4[tid + st].y;
            red4[tid].z += red4[tid + st].z; red4[tid].w += red4[tid + st].w;
        }
        __syncthreads();
    }
    if (tid < 32) {
        float4 t = red4[tid];
        const float mn = pmn2[tid >> 4];
        t.x += mn; t.y += mn; t.z += mn; t.w += mn;
        *(float4*)(&pout[((size_t)(bh * 4 + chunk)) * ND + tid * 4]) = t;
    }

    // ---- phase e: last-block merge + finish for this bh ----
    __threadfence();                       // publish pout/ppr/stats/tailsc
    if (tid == 0) ticket = atomicAdd(&counters[bh], 1);
    __syncthreads();
    if (ticket != 3) return;
    __threadfence();                       // acquire: observe all 4 chunks

    if (tid < 64) sred[tid] = tailsc[bh * 64 + tid];   // ts[] in sred
    __syncthreads();

    if (tid < 128) {
        const int d = tid;
        float msp[4], zsp[4];
#pragma unroll
        for (int sp = 0; sp < 4; ++sp) {
            msp[sp] = stats[(size_t)(bh * 4 + sp) * 2];
            zsp[sp] = stats[(size_t)(bh * 4 + sp) * 2 + 1];
        }
        float mg = fmaxf(fmaxf(msp[0], msp[1]), fmaxf(msp[2], msp[3]));
        for (int t = 0; t < 64; ++t) mg = fmaxf(mg, sred[t]);

        float wsp[4], zg = 0.f;
#pragma unroll
        for (int sp = 0; sp < 4; ++sp) { wsp[sp] = expf(msp[sp] - mg); zg += wsp[sp] * zsp[sp]; }
        for (int t = 0; t < 64; ++t) zg += expf(sred[t] - mg);

        float oacc = 0.f;
        float prx = 0.f, pry = 0.f, prz = 0.f, prw = 0.f;
#pragma unroll
        for (int sp = 0; sp < 4; ++sp) {
            oacc += wsp[sp] * pout[((size_t)(bh * 4 + sp)) * ND + d];
            float4 t = *(const float4*)(&ppr[(size_t)(bh * 4 + sp) * 4]);
            prx += wsp[sp] * t.x; pry += wsp[sp] * t.y;
            prz += wsp[sp] * t.z; prw += wsp[sp] * t.w;
        }
        float4 vp = *(const float4*)(&valp[((size_t)bh * ND + d) * 4]);
        oacc += prx * vp.x + pry * vp.y + prz * vp.z + prw * vp.w;

        for (int t = 0; t < NSF; ++t) {
            const float w = expf(sred[t] - mg);
            oacc += w * __builtin_nontemporal_load(&vfull[((size_t)bh * NSF + t) * ND + d]);
        }
        oacc += expf(sred[NSF] - mg) * v_raw[bh * ND + d];

        attn_out[bh * ND + d] = oacc / zg;
    }
}

// ---------------------------------------------------------------------------
extern "C" void kernel_launch(void* const* d_in, const int* in_sizes, int n_in,
                              void* d_out, int out_size, void* d_ws, size_t ws_size,
                              hipStream_t stream) {
    const float* hs    = (const float*)d_in[0];
    const float* wq    = (const float*)d_in[1];
    const float* wk    = (const float*)d_in[2];
    const float* wv    = (const float*)d_in[3];
    const float* wo    = (const float*)d_in[4];
    const int*   pos   = (const int*)  d_in[5];
    const int*   kq    = (const int*)  d_in[6];
    const float* ksc   = (const float*)d_in[7];
    const float* kmn   = (const float*)d_in[8];
    const float* kfull = (const float*)d_in[9];
    const float* keyp  = (const float*)d_in[10];
    const float* keyq  = (const float*)d_in[11];
    const int*   vq    = (const int*)  d_in[12];
    const float* vsc   = (const float*)d_in[13];
    const float* vmn   = (const float*)d_in[14];
    const float* vfull = (const float*)d_in[15];
    const float* valq  = (const float*)d_in[16];
    const float* valp  = (const float*)d_in[17];

    float* ws = (float*)d_ws;
    float* q_raw   = ws;                 // 16384
    float* k_raw   = q_raw  + 16384;     // 16384
    float* v_raw   = k_raw  + 16384;     // 16384
    float* tailsc  = v_raw  + 16384;     // 8192
    float* stats   = tailsc + 8192;      // 1024
    float* pout    = stats  + 1024;      // 65536
    float* ppr     = pout   + 65536;     // 2048
    float* attno   = ppr    + 2048;      // 16384
    int*   counters= (int*)(attno + 16384); // 128 ints

    hipMemsetAsync(counters, 0, NBH * sizeof(int), stream);

    gemv8_qkv_kernel<<<1536, 256, 0, stream>>>(wq, wk, wv, hs, q_raw, k_raw, v_raw);

    fused_attn_kernel<<<512, 256, 0, stream>>>(kq, ksc, kmn, keyp,
                                               vq, vsc, vmn, valq,
                                               q_raw, k_raw, v_raw, pos, keyq, kfull,
                                               valp, vfull,
                                               tailsc, stats, pout, ppr,
                                               counters, attno);

    gemv8_kernel<<<512, 256, 0, stream>>>(wo, attno, (float*)d_out);
}

// Round 12
// 181.861 us; speedup vs baseline: 1.7036x; 1.7036x over previous
//
#include <hip/hip_runtime.h>

#define NB   4
#define NH   32
#define ND   128
#define NHID 4096
#define NSQ  4096
#define NSF  63
#define NST  4160      // NSQ + NSF + 1
#define NBH  128       // NB * NH

typedef int   v4i __attribute__((ext_vector_type(4)));
typedef float v4f __attribute__((ext_vector_type(4)));
typedef float v2f __attribute__((ext_vector_type(2)));

// ---------------------------------------------------------------------------
// GEMV: Y[b, j] = sum_i X[b, i] * W[j, i]   (W row-major HIDxHID)
// 8 rows per block, 4 batches simultaneously; X tile staged in LDS.
// ---------------------------------------------------------------------------
__device__ __forceinline__ void gemv8_body(const float* __restrict__ W,
                                           const float* __restrict__ X,
                                           float* __restrict__ Y,
                                           int blk) {
    __shared__ float4 xs[4][256];
    __shared__ float  wred[32][4];
    const int tid  = threadIdx.x;
    const int row0 = blk * 8;

    float acc[8][4];
#pragma unroll
    for (int r = 0; r < 8; ++r)
#pragma unroll
        for (int b = 0; b < 4; ++b) acc[r][b] = 0.f;

    for (int kt = 0; kt < 4; ++kt) {
        const int kb = kt * 1024;
#pragma unroll
        for (int b = 0; b < 4; ++b)
            xs[b][tid] = *(const float4*)(&X[b * NHID + kb + tid * 4]);
        __syncthreads();
#pragma unroll
        for (int r = 0; r < 8; ++r) {
            v4f w = __builtin_nontemporal_load(
                        (const v4f*)&W[(size_t)(row0 + r) * NHID + kb + tid * 4]);
#pragma unroll
            for (int b = 0; b < 4; ++b) {
                float4 x = xs[b][tid];
                acc[r][b] += w.x * x.x + w.y * x.y + w.z * x.z + w.w * x.w;
            }
        }
        __syncthreads();
    }

    const int lane = tid & 63, wave = tid >> 6;
#pragma unroll
    for (int o = 0; o < 32; ++o) {
        float v = acc[o >> 2][o & 3];
#pragma unroll
        for (int off = 32; off; off >>= 1) v += __shfl_down(v, off, 64);
        if (lane == 0) wred[o][wave] = v;
    }
    __syncthreads();
    if (tid < 32) {
        float v = wred[tid][0] + wred[tid][1] + wred[tid][2] + wred[tid][3];
        Y[(size_t)(tid & 3) * NHID + row0 + (tid >> 2)] = v;
    }
}

__global__ __launch_bounds__(256) void gemv8_kernel(const float* __restrict__ W,
                                                    const float* __restrict__ X,
                                                    float* __restrict__ Y) {
    gemv8_body(W, X, Y, blockIdx.x);
}

// grid = 1536: blocks [0,512) -> wq, [512,1024) -> wk, [1024,1536) -> wv
__global__ __launch_bounds__(256) void gemv8_qkv_kernel(const float* __restrict__ wq,
                                                        const float* __restrict__ wk,
                                                        const float* __restrict__ wv,
                                                        const float* __restrict__ X,
                                                        float* __restrict__ q,
                                                        float* __restrict__ k,
                                                        float* __restrict__ v) {
    const int which = blockIdx.x >> 9;
    const int blk   = blockIdx.x & 511;
    const float* W = (which == 0) ? wq : (which == 1) ? wk : wv;
    float*       Y = (which == 0) ? q  : (which == 1) ? k  : v;
    gemv8_body(W, X, Y, blk);
}

// ---------------------------------------------------------------------------
// Fused flash split WITH INLINE RoPE: per (bh, chunk of 1024 s):
//   rope(q,k) + qr in LDS -> quant-K scores + low-rank -> local softmax ->
//   quant-V partial + low-rank partial. chunk==0 also emits the 64 raw
//   tail scores (k_full + new k). grid = NBH*4, 256 threads.
// NOTE: cross-block dataflow stays behind kernel boundaries — cooperative
// grid.sync (r9) and atomic-ticket finish (r11) both invalidate per-XCD L2
// per sync and cost 1.7-2.2x. Do not re-fuse across blocks on this chip.
// ---------------------------------------------------------------------------
__global__ __launch_bounds__(256) void fused_attn_kernel(const int*   __restrict__ kq,
                                                         const float* __restrict__ ksc,
                                                         const float* __restrict__ kmn,
                                                         const float* __restrict__ keyp,
                                                         const int*   __restrict__ vq,
                                                         const float* __restrict__ vsc,
                                                         const float* __restrict__ vmn,
                                                         const float* __restrict__ valq,
                                                         const float* __restrict__ q_raw,
                                                         const float* __restrict__ k_raw,
                                                         const int*   __restrict__ pos_ids,
                                                         const float* __restrict__ keyq,
                                                         const float* __restrict__ kfull,
                                                         float* __restrict__ tailsc,
                                                         float* __restrict__ stats,
                                                         float* __restrict__ pout,
                                                         float* __restrict__ ppr) {
    const int bh     = blockIdx.x >> 2;
    const int chunk  = blockIdx.x & 3;
    const int tid    = threadIdx.x;
    const int b      = bh >> 5;
    const int base   = bh * ND;
    const int gbase  = chunk * 16;
    const int schunk = chunk * 1024;

    __shared__ float  qsh[128], ksh[128];
    __shared__ float4 rred[128];
    __shared__ float  qr4v[4];
    __shared__ float  qs[128][16];     // q[d] * k_scale[d][g]
    __shared__ float  mt[128][16];     // q[d] * k_mn[d][g] -> reduced over d
    __shared__ float  psc[1024][2];    // p[s] * v_scale[s][g]
    __shared__ float  sred[256];
    __shared__ float2 red2[256];
    __shared__ float4 red4[256];
    __shared__ float  pmn2[2];

    // ---- phase 0: inline RoPE + qr reduction ----
    if (tid < 128) {
        const int d = tid;
        const double pos  = (double)pos_ids[b];              // QL == 1
        const int    j    = d & 63;
        const double invf = pow(10000.0, -(double)(2 * j) / 128.0);
        const double ang  = pos * invf;
        const float  c = (float)cos(ang), s = (float)sin(ang);

        const float qv = q_raw[base + d], kv = k_raw[base + d];
        const float qh = (d < 64) ? -q_raw[base + d + 64] : q_raw[base + d - 64];
        const float kh = (d < 64) ? -k_raw[base + d + 64] : k_raw[base + d - 64];
        const float qo = qv * c + qh * s;
        const float ko = kv * c + kh * s;
        qsh[d] = qo;
        ksh[d] = ko;

        float4 kq4 = *(const float4*)(&keyq[(size_t)(base + d) * 4]);
        rred[d] = make_float4(qo * kq4.x, qo * kq4.y, qo * kq4.z, qo * kq4.w);
    }
    __syncthreads();
    for (int st = 64; st; st >>= 1) {
        if (tid < st) {
            rred[tid].x += rred[tid + st].x; rred[tid].y += rred[tid + st].y;
            rred[tid].z += rred[tid + st].z; rred[tid].w += rred[tid + st].w;
        }
        __syncthreads();
    }
    if (tid == 0) {
        qr4v[0] = rred[0].x; qr4v[1] = rred[0].y;
        qr4v[2] = rred[0].z; qr4v[3] = rred[0].w;
    }

    // ---- chunk 0 extra: raw tail scores (k_full rows + new roped k) ----
    if (chunk == 0) {
        const int lane = tid & 63, wave = tid >> 6;
        for (int t = wave; t < 64; t += 4) {
            const int d = lane * 2;
            float v;
            if (t < 63) {
                v2f r2 = __builtin_nontemporal_load(
                             (const v2f*)&kfull[((size_t)bh * NSF + t) * ND + d]);
                v = qsh[d] * r2.x + qsh[d + 1] * r2.y;
            } else {
                v = qsh[d] * ksh[d] + qsh[d + 1] * ksh[d + 1];
            }
#pragma unroll
            for (int off = 32; off; off >>= 1) v += __shfl_down(v, off, 64);
            if (lane == 0) tailsc[bh * 64 + t] = v * 0.08838834764831845f;
        }
    }
    __syncthreads();

    // ---- phase a: stage q*scale, reduce q*mn over d ----
    {
        const int d = tid >> 1, half = tid & 1;
        const float q = qsh[d];
        const float* scp = &ksc[((size_t)bh * ND + d) * 64 + gbase + half * 8];
        const float* mnp = &kmn[((size_t)bh * ND + d) * 64 + gbase + half * 8];
        v4f a = __builtin_nontemporal_load((const v4f*)(scp));
        v4f c = __builtin_nontemporal_load((const v4f*)(scp + 4));
        qs[d][half * 8 + 0] = q * a.x; qs[d][half * 8 + 1] = q * a.y;
        qs[d][half * 8 + 2] = q * a.z; qs[d][half * 8 + 3] = q * a.w;
        qs[d][half * 8 + 4] = q * c.x; qs[d][half * 8 + 5] = q * c.y;
        qs[d][half * 8 + 6] = q * c.z; qs[d][half * 8 + 7] = q * c.w;
        v4f m0 = __builtin_nontemporal_load((const v4f*)(mnp));
        v4f m1 = __builtin_nontemporal_load((const v4f*)(mnp + 4));
        mt[d][half * 8 + 0] = q * m0.x; mt[d][half * 8 + 1] = q * m0.y;
        mt[d][half * 8 + 2] = q * m0.z; mt[d][half * 8 + 3] = q * m0.w;
        mt[d][half * 8 + 4] = q * m1.x; mt[d][half * 8 + 5] = q * m1.y;
        mt[d][half * 8 + 6] = q * m1.z; mt[d][half * 8 + 7] = q * m1.w;
    }
    __syncthreads();
    for (int st = 64; st; st >>= 1) {
        for (int idx = tid; idx < st * 16; idx += 256) {
            const int dd = idx >> 4, g = idx & 15;
            mt[dd][g] += mt[dd + st][g];
        }
        __syncthreads();
    }

    // ---- phase b: scores for s0..s0+3 ----
    const int s0 = schunk + tid * 4;
    const int g  = tid >> 4;
    const int* kcol = kq + (size_t)bh * ND * NSQ + s0;

    float a0 = 0.f, a1 = 0.f, a2 = 0.f, a3 = 0.f;
#pragma unroll 8
    for (int d = 0; d < ND; ++d) {
        v4i c = __builtin_nontemporal_load((const v4i*)&kcol[(size_t)d * NSQ]);
        const float w = qs[d][g];
        a0 += w * (float)c.x; a1 += w * (float)c.y;
        a2 += w * (float)c.z; a3 += w * (float)c.w;
    }
    const float mnsum = mt[0][g];
    const float4 q4 = make_float4(qr4v[0], qr4v[1], qr4v[2], qr4v[3]);

    float sc4[4] = {a0, a1, a2, a3};
#pragma unroll
    for (int j = 0; j < 4; ++j) {
        v4f kp = __builtin_nontemporal_load(
                     (const v4f*)&keyp[((size_t)bh * NSQ + s0 + j) * 4]);
        sc4[j] = (sc4[j] + mnsum + q4.x * kp.x + q4.y * kp.y + q4.z * kp.z + q4.w * kp.w)
                 * 0.08838834764831845f;
    }

    // ---- phase c: local softmax over this block's 1024 scores ----
    float mloc = fmaxf(fmaxf(sc4[0], sc4[1]), fmaxf(sc4[2], sc4[3]));
    sred[tid] = mloc; __syncthreads();
    for (int st = 128; st; st >>= 1) {
        if (tid < st) sred[tid] = fmaxf(sred[tid], sred[tid + st]);
        __syncthreads();
    }
    mloc = sred[0]; __syncthreads();

    float p[4];
    float z = 0.f;
#pragma unroll
    for (int j = 0; j < 4; ++j) { p[j] = expf(sc4[j] - mloc); z += p[j]; }

    const int l0 = tid * 4;
    float2 pmn_loc = make_float2(0.f, 0.f);
    float4 pr4 = make_float4(0.f, 0.f, 0.f, 0.f);
#pragma unroll
    for (int j = 0; j < 4; ++j) {
        const int s = s0 + j;
        v2f sc = __builtin_nontemporal_load((const v2f*)&vsc[((size_t)bh * NSQ + s) * 2]);
        v2f mn = __builtin_nontemporal_load((const v2f*)&vmn[((size_t)bh * NSQ + s) * 2]);
        psc[l0 + j][0] = p[j] * sc.x;
        psc[l0 + j][1] = p[j] * sc.y;
        pmn_loc.x += p[j] * mn.x; pmn_loc.y += p[j] * mn.y;
        v4f vr = __builtin_nontemporal_load((const v4f*)&valq[((size_t)bh * NSQ + s) * 4]);
        pr4.x += p[j] * vr.x; pr4.y += p[j] * vr.y;
        pr4.z += p[j] * vr.z; pr4.w += p[j] * vr.w;
    }
    sred[tid] = z; red2[tid] = pmn_loc; red4[tid] = pr4;
    __syncthreads();
    for (int st = 128; st; st >>= 1) {
        if (tid < st) {
            sred[tid] += sred[tid + st];
            red2[tid].x += red2[tid + st].x; red2[tid].y += red2[tid + st].y;
            red4[tid].x += red4[tid + st].x; red4[tid].y += red4[tid + st].y;
            red4[tid].z += red4[tid + st].z; red4[tid].w += red4[tid + st].w;
        }
        __syncthreads();
    }
    if (tid == 0) {
        stats[(size_t)(bh * 4 + chunk) * 2]     = mloc;
        stats[(size_t)(bh * 4 + chunk) * 2 + 1] = sred[0];
        *(float4*)(&ppr[(size_t)(bh * 4 + chunk) * 4]) = red4[0];
        pmn2[0] = red2[0].x; pmn2[1] = red2[0].y;
    }
    __syncthreads();

    // ---- phase d: quantized-V partial over 1024 s-rows ----
    const int r      = tid >> 5;
    const int lane32 = tid & 31;
    const int d4     = lane32 * 4;
    const int gv     = lane32 >> 4;

    const int* vbase = vq + ((size_t)bh * NSQ + schunk) * ND + d4;

    float4 acc = make_float4(0.f, 0.f, 0.f, 0.f);
#pragma unroll 8
    for (int k0 = 0; k0 < 1024; k0 += 8) {
        const int kk = k0 + r;
        v4i c = __builtin_nontemporal_load((const v4i*)&vbase[(size_t)kk * ND]);
        const float w = psc[kk][gv];
        acc.x += w * (float)c.x; acc.y += w * (float)c.y;
        acc.z += w * (float)c.z; acc.w += w * (float)c.w;
    }
    red4[tid] = acc;
    __syncthreads();
    for (int st = 128; st >= 32; st >>= 1) {
        if (tid < st) {
            red4[tid].x += red4[tid + st].x; red4[tid].y += red4[tid + st].y;
            red4[tid].z += red4[tid + st].z; red4[tid].w += red4[tid + st].w;
        }
        __syncthreads();
    }
    if (tid < 32) {
        float4 t = red4[tid];
        const float mn = pmn2[tid >> 4];
        t.x += mn; t.y += mn; t.z += mn; t.w += mn;
        *(float4*)(&pout[((size_t)(bh * 4 + chunk)) * ND + tid * 4]) = t;
    }
}

// ---------------------------------------------------------------------------
// Finish: merge 4 splits + 64-tail with max-rescaling, add low-rank V and
// full-precision V tail, normalize. grid = 128 (bh), 128 threads (d).
// ---------------------------------------------------------------------------
__global__ __launch_bounds__(128) void pv_finish_kernel(const float* __restrict__ pout,
                                                        const float* __restrict__ ppr,
                                                        const float* __restrict__ stats,
                                                        const float* __restrict__ tailsc,
                                                        const float* __restrict__ valp,
                                                        const float* __restrict__ vfull,
                                                        const float* __restrict__ vraw,
                                                        float* __restrict__ attn_out) {
    const int bh = blockIdx.x;
    const int d  = threadIdx.x;

    __shared__ float ts[64];
    if (d < 64) ts[d] = tailsc[bh * 64 + d];
    __syncthreads();

    float msp[4], zsp[4];
#pragma unroll
    for (int sp = 0; sp < 4; ++sp) {
        msp[sp] = stats[(size_t)(bh * 4 + sp) * 2];
        zsp[sp] = stats[(size_t)(bh * 4 + sp) * 2 + 1];
    }
    float mg = fmaxf(fmaxf(msp[0], msp[1]), fmaxf(msp[2], msp[3]));
    for (int t = 0; t < 64; ++t) mg = fmaxf(mg, ts[t]);

    float wsp[4], zg = 0.f;
#pragma unroll
    for (int sp = 0; sp < 4; ++sp) { wsp[sp] = expf(msp[sp] - mg); zg += wsp[sp] * zsp[sp]; }
    for (int t = 0; t < 64; ++t) zg += expf(ts[t] - mg);

    float acc = 0.f;
    float prx = 0.f, pry = 0.f, prz = 0.f, prw = 0.f;
#pragma unroll
    for (int sp = 0; sp < 4; ++sp) {
        acc += wsp[sp] * pout[((size_t)(bh * 4 + sp)) * ND + d];
        float4 t = *(const float4*)(&ppr[(size_t)(bh * 4 + sp) * 4]);
        prx += wsp[sp] * t.x; pry += wsp[sp] * t.y;
        prz += wsp[sp] * t.z; prw += wsp[sp] * t.w;
    }
    float4 vp = *(const float4*)(&valp[((size_t)bh * ND + d) * 4]);
    acc += prx * vp.x + pry * vp.y + prz * vp.z + prw * vp.w;

    for (int t = 0; t < NSF; ++t) {
        const float w = expf(ts[t] - mg);
        acc += w * __builtin_nontemporal_load(&vfull[((size_t)bh * NSF + t) * ND + d]);
    }
    acc += expf(ts[NSF] - mg) * vraw[bh * ND + d];

    attn_out[bh * ND + d] = acc / zg;
}

// ---------------------------------------------------------------------------
extern "C" void kernel_launch(void* const* d_in, const int* in_sizes, int n_in,
                              void* d_out, int out_size, void* d_ws, size_t ws_size,
                              hipStream_t stream) {
    const float* hs    = (const float*)d_in[0];
    const float* wq    = (const float*)d_in[1];
    const float* wk    = (const float*)d_in[2];
    const float* wv    = (const float*)d_in[3];
    const float* wo    = (const float*)d_in[4];
    const int*   pos   = (const int*)  d_in[5];
    const int*   kq    = (const int*)  d_in[6];
    const float* ksc   = (const float*)d_in[7];
    const float* kmn   = (const float*)d_in[8];
    const float* kfull = (const float*)d_in[9];
    const float* keyp  = (const float*)d_in[10];
    const float* keyq  = (const float*)d_in[11];
    const int*   vq    = (const int*)  d_in[12];
    const float* vsc   = (const float*)d_in[13];
    const float* vmn   = (const float*)d_in[14];
    const float* vfull = (const float*)d_in[15];
    const float* valq  = (const float*)d_in[16];
    const float* valp  = (const float*)d_in[17];

    float* ws = (float*)d_ws;
    float* q_raw   = ws;                 // 16384
    float* k_raw   = q_raw  + 16384;     // 16384
    float* v_raw   = k_raw  + 16384;     // 16384
    float* tailsc  = v_raw  + 16384;     // 8192
    float* stats   = tailsc + 8192;      // 1024
    float* pout    = stats  + 1024;      // 65536
    float* ppr     = pout   + 65536;     // 2048
    float* attno   = ppr    + 2048;      // 16384

    gemv8_qkv_kernel<<<1536, 256, 0, stream>>>(wq, wk, wv, hs, q_raw, k_raw, v_raw);

    fused_attn_kernel<<<512, 256, 0, stream>>>(kq, ksc, kmn, keyp,
                                               vq, vsc, vmn, valq,
                                               q_raw, k_raw, pos, keyq, kfull,
                                               tailsc, stats, pout, ppr);

    pv_finish_kernel<<<128, 128, 0, stream>>>(pout, ppr, stats, tailsc,
                                              valp, vfull, v_raw, attno);

    gemv8_kernel<<<512, 256, 0, stream>>>(wo, attno, (float*)d_out);
}